// Round 13
// baseline (1483.318 us; speedup 1.0000x reference)
//
#include <hip/hip_runtime.h>
#include <math.h>

#define BB   128
#define TT   256
#define IN0  300
#define HID  512
#define G3   1536
#define EPSV 1e-5f
#define WPAD 520          // bf16 elems per LDS row (512 + 8 pad)

typedef __attribute__((ext_vector_type(8))) short bf16x8;
typedef __attribute__((ext_vector_type(4))) float f32x4;

__device__ __forceinline__ float sigm(float x) { return 1.0f / (1.0f + expf(-x)); }

__device__ __forceinline__ unsigned short f2bf(float f) {
    union { float f; unsigned u; } v; v.f = f;
    unsigned r = v.u + 0x7fffu + ((v.u >> 16) & 1u);   // RNE
    return (unsigned short)(r >> 16);
}

__device__ __forceinline__ float bf2f(unsigned short u) {
    union { unsigned u; float f; } v; v.u = ((unsigned)u) << 16; return v.f;
}

// ---------------- bf16-MFMA xg GEMM; OUTPUT NOW bf16 (packed pair stores) ----------------
__global__ __launch_bounds__(256) void gemm_mfma_bias(
    const float* __restrict__ A, const float* __restrict__ Bm,
    const float* __restrict__ bias, unsigned short* __restrict__ C,
    int K, int c, int Tc)
{
    __shared__ unsigned short Abf[128][40];
    __shared__ unsigned short Bbf[128][40];

    const int n0  = blockIdx.x * 128;
    const int m0  = blockIdx.y * 128;
    const int tid = threadIdx.x;
    const int wvi = tid >> 6;
    const int ln  = tid & 63;
    const int qr  = (wvi >> 1) * 64;
    const int qc  = (wvi & 1) * 64;
    const int frow = ln & 15;
    const int koff = (ln >> 4) * 8;

    f32x4 acc[4][4];
#pragma unroll
    for (int i = 0; i < 4; ++i)
#pragma unroll
        for (int j = 0; j < 4; ++j) acc[i][j] = (f32x4){0.f, 0.f, 0.f, 0.f};

    const int lr = tid >> 1;
    const int lc = (tid & 1) * 16;

    const int gr   = m0 + lr;
    const int brow = gr / Tc;
    const int tl   = gr - brow * Tc;
    const float* Arow = A + ((size_t)brow * TT + (size_t)(c + tl)) * K;
    const float* Brow = Bm + (size_t)(n0 + lr) * K;

    const int nk = (K + 31) >> 5;
    for (int kt = 0; kt < nk; ++kt) {
        const int k0 = kt * 32;
        float a[16], b[16];
        if (k0 + 32 <= K) {
            float4 v;
#pragma unroll
            for (int j = 0; j < 4; ++j) {
                v = *(const float4*)(Arow + k0 + lc + j * 4);
                a[j*4+0] = v.x; a[j*4+1] = v.y; a[j*4+2] = v.z; a[j*4+3] = v.w;
                v = *(const float4*)(Brow + k0 + lc + j * 4);
                b[j*4+0] = v.x; b[j*4+1] = v.y; b[j*4+2] = v.z; b[j*4+3] = v.w;
            }
        } else {
#pragma unroll
            for (int j = 0; j < 16; ++j) {
                const int gk = k0 + lc + j;
                a[j] = (gk < K) ? Arow[gk] : 0.f;
                b[j] = (gk < K) ? Brow[gk] : 0.f;
            }
        }
        bf16x8 pa0, pa1, pb0, pb1;
#pragma unroll
        for (int j = 0; j < 8; ++j) {
            pa0[j] = (short)f2bf(a[j]);     pa1[j] = (short)f2bf(a[8 + j]);
            pb0[j] = (short)f2bf(b[j]);     pb1[j] = (short)f2bf(b[8 + j]);
        }
        *(bf16x8*)&Abf[lr][lc]     = pa0;
        *(bf16x8*)&Abf[lr][lc + 8] = pa1;
        *(bf16x8*)&Bbf[lr][lc]     = pb0;
        *(bf16x8*)&Bbf[lr][lc + 8] = pb1;
        __syncthreads();

        bf16x8 af[4], bfv[4];
#pragma unroll
        for (int rt = 0; rt < 4; ++rt)
            af[rt] = *(const bf16x8*)&Abf[qr + rt * 16 + frow][koff];
#pragma unroll
        for (int ct = 0; ct < 4; ++ct)
            bfv[ct] = *(const bf16x8*)&Bbf[qc + ct * 16 + frow][koff];
#pragma unroll
        for (int rt = 0; rt < 4; ++rt)
#pragma unroll
            for (int ct = 0; ct < 4; ++ct)
                acc[rt][ct] = __builtin_amdgcn_mfma_f32_16x16x32_bf16(
                    af[rt], bfv[ct], acc[rt][ct], 0, 0, 0);
        __syncthreads();
    }

    // epilogue: bias add in fp32, pack bf16 pairs via shfl, even lanes store u32
#pragma unroll
    for (int ct = 0; ct < 4; ++ct) {
        const int colg = n0 + qc + ct * 16 + (ln & 15);
        const float bv = bias[colg];
#pragma unroll
        for (int rt = 0; rt < 4; ++rt) {
#pragma unroll
            for (int i = 0; i < 4; ++i) {
                const int rowg = m0 + qr + rt * 16 + (ln >> 4) * 4 + i;
                const float v = acc[rt][ct][i] + bv;
                const float o = __shfl_xor(v, 1);
                if (!(ln & 1)) {
                    const unsigned pk = (unsigned)f2bf(v) | ((unsigned)f2bf(o) << 16);
                    *(unsigned*)&C[(size_t)rowg * G3 + colg] = pk;
                }
            }
        }
    }
}

// ---------------- fused two-layer persistent recurrence (xg now bf16) ----------------
__global__ __launch_bounds__(256) void fused_rec(
    const unsigned short* __restrict__ xg,   // (B, Tc, 1536) bf16 layer-0 x-gates
    const float* __restrict__ w_hh0, const float* __restrict__ b_hh0,
    const float* __restrict__ w_hh1, const float* __restrict__ b_hh1,
    const float* __restrict__ w_ih1, const float* __restrict__ b_ih1,
    unsigned short* __restrict__ y0bf, // (B, T, H) bf16 layer-0 output
    float* __restrict__ h32_0, float* __restrict__ h32_1,
    unsigned short* __restrict__ hbf0, unsigned short* __restrict__ hbf1,
    unsigned int* __restrict__ flags0, unsigned int* __restrict__ flags1,
    int t0, int Tc)
{
    __shared__ unsigned short wldsA[48 * WPAD];
    __shared__ unsigned short wldsB[48 * WPAD];
    __shared__ unsigned short bufA[16 * WPAD];
    __shared__ unsigned short bufB[16 * WPAD];
    __shared__ float gpatch[6][16][17];

    const int tid = threadIdx.x;
    const int wv  = tid >> 6;
    const int ln  = tid & 63;
    const int r   = tid >> 4;
    const int c   = tid & 15;
    const int frow = ln & 15;
    const int koff = (ln >> 4) * 8;

    if (blockIdx.x < 128) {
        // ================= layer 0 =================
        const int wg  = blockIdx.x;
        const int bg  = wg >> 5;
        const int jg  = wg & 31;
        const int b0A = bg * 32;
        const int b0B = bg * 32 + 16;
        const int j0  = jg * 16;

        unsigned int phase = 0;
        unsigned int* flagp = &flags0[bg * 32 + jg];
        unsigned int* pollp = &flags0[bg * 32 + (ln & 31)];

        for (int i = tid; i < 48 * 512; i += 256) {
            const int row = i >> 9, col = i & 511;
            const int grow = (row >> 4) * HID + j0 + (row & 15);
            wldsA[row * WPAD + col] = f2bf(w_hh0[(size_t)grow * HID + col]);
        }

        const float bh0 = b_hh0[j0 + c];
        const float bh1 = b_hh0[HID + j0 + c];
        const float bh2 = b_hh0[2 * HID + j0 + c];

        unsigned short* hx0 = hbf0;
        unsigned short* hx1 = hbf0 + BB * HID;

        float hA, hB;
        if (t0 == 0) {
            hA = hB = 0.f;
            if (!(tid & 1)) {
                __hip_atomic_store((unsigned*)&hx0[(size_t)(b0A + r) * HID + j0 + c], 0u,
                                   __ATOMIC_RELAXED, __HIP_MEMORY_SCOPE_SYSTEM);
                __hip_atomic_store((unsigned*)&hx0[(size_t)(b0B + r) * HID + j0 + c], 0u,
                                   __ATOMIC_RELAXED, __HIP_MEMORY_SCOPE_SYSTEM);
            }
        } else {
            hA = h32_0[(size_t)(b0A + r) * HID + j0 + c];
            hB = h32_0[(size_t)(b0B + r) * HID + j0 + c];
        }
        __syncthreads();
        ++phase;
        if (tid == 0)
            __hip_atomic_store(flagp, phase, __ATOMIC_RELAXED, __HIP_MEMORY_SCOPE_SYSTEM);
        while (true) {
            unsigned v = __hip_atomic_load(pollp, __ATOMIC_RELAXED, __HIP_MEMORY_SCOPE_SYSTEM);
            if (__all(v >= phase)) break;
            __builtin_amdgcn_s_sleep(2);
        }
        __syncthreads();

        const unsigned short* xrA = xg + ((size_t)(b0A + r) * Tc) * G3 + j0 + c;
        const unsigned short* xrB = xg + ((size_t)(b0B + r) * Tc) * G3 + j0 + c;
        float xA0 = bf2f(xrA[0]), xA1 = bf2f(xrA[HID]), xA2 = bf2f(xrA[2 * HID]);
        float xB0 = bf2f(xrB[0]), xB1 = bf2f(xrB[HID]), xB2 = bf2f(xrB[2 * HID]);

        for (int s = 0; s < Tc; ++s) {
            const int t = t0 + s;
            const unsigned short* hprev = (t & 1) ? hx1 : hx0;
            unsigned short*       hnext = (t & 1) ? hx0 : hx1;

            {
                const unsigned long long* srcA =
                    (const unsigned long long*)(hprev + (size_t)b0A * HID);
                const unsigned long long* srcB =
                    (const unsigned long long*)(hprev + (size_t)b0B * HID);
#pragma unroll
                for (int k = 0; k < 8; ++k) {
                    const int i = k * 256 + tid;
                    const int row = i >> 7;
                    const int q   = i & 127;
                    unsigned long long vA = __hip_atomic_load(srcA + row * 128 + q,
                            __ATOMIC_RELAXED, __HIP_MEMORY_SCOPE_SYSTEM);
                    unsigned long long vB = __hip_atomic_load(srcB + row * 128 + q,
                            __ATOMIC_RELAXED, __HIP_MEMORY_SCOPE_SYSTEM);
                    *(unsigned long long*)&bufA[row * WPAD + q * 4] = vA;
                    *(unsigned long long*)&bufB[row * WPAD + q * 4] = vB;
                }
            }
            __syncthreads();

            {
                auto chain = [&](int cid) {
                    const int half = (cid >= 3) ? 1 : 0;
                    const int g    = cid - half * 3;
                    const unsigned short* arow =
                        (half ? bufB : bufA) + frow * WPAD + koff;
                    const unsigned short* brow = wldsA + (g * 16 + frow) * WPAD + koff;
                    f32x4 acc = {0.f, 0.f, 0.f, 0.f};
#pragma unroll
                    for (int ks = 0; ks < 16; ++ks)
                        acc = __builtin_amdgcn_mfma_f32_16x16x32_bf16(
                            *(const bf16x8*)(arow + ks * 32),
                            *(const bf16x8*)(brow + ks * 32), acc, 0, 0, 0);
#pragma unroll
                    for (int i = 0; i < 4; ++i)
                        gpatch[cid][(ln >> 4) * 4 + i][ln & 15] = acc[i];
                };
                chain(wv);
                if (wv < 2) chain(4 + wv);
            }
            __syncthreads();

            {
                const float rr = sigm(xA0 + gpatch[0][r][c] + bh0);
                const float zz = sigm(xA1 + gpatch[1][r][c] + bh1);
                const float nn = tanhf(xA2 + rr * (gpatch[2][r][c] + bh2));
                hA = (1.f - zz) * nn + zz * hA;
            }
            {
                const float rr = sigm(xB0 + gpatch[3][r][c] + bh0);
                const float zz = sigm(xB1 + gpatch[4][r][c] + bh1);
                const float nn = tanhf(xB2 + rr * (gpatch[5][r][c] + bh2));
                hB = (1.f - zz) * nn + zz * hB;
            }

            const float oA = __shfl_xor(hA, 1);
            const float oB = __shfl_xor(hB, 1);
            if (!(tid & 1)) {
                const unsigned pA = (unsigned)f2bf(hA) | ((unsigned)f2bf(oA) << 16);
                const unsigned pB = (unsigned)f2bf(hB) | ((unsigned)f2bf(oB) << 16);
                __hip_atomic_store((unsigned*)&hnext[(size_t)(b0A + r) * HID + j0 + c], pA,
                                   __ATOMIC_RELAXED, __HIP_MEMORY_SCOPE_SYSTEM);
                __hip_atomic_store((unsigned*)&hnext[(size_t)(b0B + r) * HID + j0 + c], pB,
                                   __ATOMIC_RELAXED, __HIP_MEMORY_SCOPE_SYSTEM);
                __hip_atomic_store((unsigned*)&y0bf[((size_t)(b0A + r) * TT + t) * HID + j0 + c],
                                   pA, __ATOMIC_RELAXED, __HIP_MEMORY_SCOPE_SYSTEM);
                __hip_atomic_store((unsigned*)&y0bf[((size_t)(b0B + r) * TT + t) * HID + j0 + c],
                                   pB, __ATOMIC_RELAXED, __HIP_MEMORY_SCOPE_SYSTEM);
            }

            __syncthreads();
            ++phase;
            if (tid == 0)
                __hip_atomic_store(flagp, phase, __ATOMIC_RELAXED, __HIP_MEMORY_SCOPE_SYSTEM);

            if (s + 1 < Tc) {
                const unsigned short* nA = xg + ((size_t)(b0A + r) * Tc + (s + 1)) * G3 + j0 + c;
                const unsigned short* nB = xg + ((size_t)(b0B + r) * Tc + (s + 1)) * G3 + j0 + c;
                xA0 = bf2f(nA[0]); xA1 = bf2f(nA[HID]); xA2 = bf2f(nA[2 * HID]);
                xB0 = bf2f(nB[0]); xB1 = bf2f(nB[HID]); xB2 = bf2f(nB[2 * HID]);
            }

            while (true) {
                unsigned v = __hip_atomic_load(pollp, __ATOMIC_RELAXED,
                                               __HIP_MEMORY_SCOPE_SYSTEM);
                if (__all(v >= phase)) break;
                __builtin_amdgcn_s_sleep(2);
            }
        }

        h32_0[(size_t)(b0A + r) * HID + j0 + c] = hA;
        h32_0[(size_t)(b0B + r) * HID + j0 + c] = hB;

    } else {
        // ================= layer 1 (inline x-gates from y0; 1 LLC exposure) =================
        const int wg  = blockIdx.x - 128;
        const int bg  = wg >> 5;
        const int jg  = wg & 31;
        const int b0A = bg * 32;
        const int b0B = bg * 32 + 16;
        const int j0  = jg * 16;

        unsigned int phase = 0;
        unsigned int* flagp = &flags1[bg * 32 + jg];
        unsigned int* poll1 = &flags1[bg * 32 + (ln & 31)];
        unsigned int* poll0 = &flags0[bg * 32 + (ln & 31)];

        for (int i = tid; i < 48 * 512; i += 256) {
            const int row = i >> 9, col = i & 511;
            const int grow = (row >> 4) * HID + j0 + (row & 15);
            wldsA[row * WPAD + col] = f2bf(w_hh1[(size_t)grow * HID + col]);
            wldsB[row * WPAD + col] = f2bf(w_ih1[(size_t)grow * HID + col]);
        }

        const float bh0 = b_hh1[j0 + c];
        const float bh1 = b_hh1[HID + j0 + c];
        const float bh2 = b_hh1[2 * HID + j0 + c];
        const float bi0 = b_ih1[j0 + c];
        const float bi1 = b_ih1[HID + j0 + c];
        const float bi2 = b_ih1[2 * HID + j0 + c];

        unsigned short* hx0 = hbf1;
        unsigned short* hx1 = hbf1 + BB * HID;

        float hA, hB;
        if (t0 == 0) {
            hA = hB = 0.f;
            if (!(tid & 1)) {
                __hip_atomic_store((unsigned*)&hx0[(size_t)(b0A + r) * HID + j0 + c], 0u,
                                   __ATOMIC_RELAXED, __HIP_MEMORY_SCOPE_SYSTEM);
                __hip_atomic_store((unsigned*)&hx0[(size_t)(b0B + r) * HID + j0 + c], 0u,
                                   __ATOMIC_RELAXED, __HIP_MEMORY_SCOPE_SYSTEM);
            }
        } else {
            hA = h32_1[(size_t)(b0A + r) * HID + j0 + c];
            hB = h32_1[(size_t)(b0B + r) * HID + j0 + c];
        }
        __syncthreads();
        ++phase;   // = 1
        if (tid == 0)
            __hip_atomic_store(flagp, phase, __ATOMIC_RELAXED, __HIP_MEMORY_SCOPE_SYSTEM);
        if (wv == 0) {
            while (true) {
                unsigned v = __hip_atomic_load(poll1, __ATOMIC_RELAXED, __HIP_MEMORY_SCOPE_SYSTEM);
                if (__all(v >= phase)) break;
                __builtin_amdgcn_s_sleep(2);
            }
        } else if (wv == 1) {
            while (true) {
                unsigned v = __hip_atomic_load(poll0, __ATOMIC_RELAXED, __HIP_MEMORY_SCOPE_SYSTEM);
                if (__all(v >= 2u)) break;
                __builtin_amdgcn_s_sleep(2);
            }
        }
        __syncthreads();

        auto chains = [&]() {
            auto chain = [&](int cid) {
                const int xsel = (cid >= 3) ? 1 : 0;
                const int g    = cid - xsel * 3;
                const unsigned short* arow = (xsel ? bufB : bufA) + frow * WPAD + koff;
                const unsigned short* brow =
                    (xsel ? wldsB : wldsA) + (g * 16 + frow) * WPAD + koff;
                f32x4 acc = {0.f, 0.f, 0.f, 0.f};
#pragma unroll
                for (int ks = 0; ks < 16; ++ks)
                    acc = __builtin_amdgcn_mfma_f32_16x16x32_bf16(
                        *(const bf16x8*)(arow + ks * 32),
                        *(const bf16x8*)(brow + ks * 32), acc, 0, 0, 0);
#pragma unroll
                for (int i = 0; i < 4; ++i)
                    gpatch[cid][(ln >> 4) * 4 + i][ln & 15] = acc[i];
            };
            chain(wv);
            if (wv < 2) chain(4 + wv);
        };

        auto gate = [&](float h) {
            const float rr = sigm(gpatch[3][r][c] + bi0 + gpatch[0][r][c] + bh0);
            const float zz = sigm(gpatch[4][r][c] + bi1 + gpatch[1][r][c] + bh1);
            const float nn = tanhf(gpatch[5][r][c] + bi2 + rr * (gpatch[2][r][c] + bh2));
            return (1.f - zz) * nn + zz * h;
        };

        for (int s = 0; s < Tc; ++s) {
            const int t = t0 + s;
            const unsigned short* hprev = (t & 1) ? hx1 : hx0;
            unsigned short*       hnext = (t & 1) ? hx0 : hx1;

            unsigned long long rah[8], ray[8], rbh[8], rby[8];
            {
                const unsigned long long* hA8 =
                    (const unsigned long long*)(hprev + (size_t)b0A * HID);
#pragma unroll
                for (int k = 0; k < 8; ++k) {
                    const int i = k * 256 + tid;
                    const int row = i >> 7;
                    const int q   = i & 127;
                    rah[k] = __hip_atomic_load(hA8 + row * 128 + q,
                            __ATOMIC_RELAXED, __HIP_MEMORY_SCOPE_SYSTEM);
                    const unsigned long long* yA8 = (const unsigned long long*)
                        (y0bf + ((size_t)(b0A + row) * TT + t) * HID);
                    ray[k] = __hip_atomic_load(yA8 + q,
                            __ATOMIC_RELAXED, __HIP_MEMORY_SCOPE_SYSTEM);
                }
                const unsigned long long* hB8 =
                    (const unsigned long long*)(hprev + (size_t)b0B * HID);
#pragma unroll
                for (int k = 0; k < 8; ++k) {
                    const int i = k * 256 + tid;
                    const int row = i >> 7;
                    const int q   = i & 127;
                    rbh[k] = __hip_atomic_load(hB8 + row * 128 + q,
                            __ATOMIC_RELAXED, __HIP_MEMORY_SCOPE_SYSTEM);
                    const unsigned long long* yB8 = (const unsigned long long*)
                        (y0bf + ((size_t)(b0B + row) * TT + t) * HID);
                    rby[k] = __hip_atomic_load(yB8 + q,
                            __ATOMIC_RELAXED, __HIP_MEMORY_SCOPE_SYSTEM);
                }
            }
#pragma unroll
            for (int k = 0; k < 8; ++k) {
                const int i = k * 256 + tid;
                const int row = i >> 7;
                const int q   = i & 127;
                *(unsigned long long*)&bufA[row * WPAD + q * 4] = rah[k];
                *(unsigned long long*)&bufB[row * WPAD + q * 4] = ray[k];
            }
            __syncthreads();
            chains();                      // stream A (B loads complete underneath)
            __syncthreads();
#pragma unroll
            for (int k = 0; k < 8; ++k) {
                const int i = k * 256 + tid;
                const int row = i >> 7;
                const int q   = i & 127;
                *(unsigned long long*)&bufA[row * WPAD + q * 4] = rbh[k];
                *(unsigned long long*)&bufB[row * WPAD + q * 4] = rby[k];
            }
            hA = gate(hA);
            {
                const float oA = __shfl_xor(hA, 1);
                if (!(tid & 1)) {
                    const unsigned pA = (unsigned)f2bf(hA) | ((unsigned)f2bf(oA) << 16);
                    __hip_atomic_store((unsigned*)&hnext[(size_t)(b0A + r) * HID + j0 + c],
                                       pA, __ATOMIC_RELAXED, __HIP_MEMORY_SCOPE_SYSTEM);
                }
            }
            __syncthreads();
            chains();                      // stream B
            __syncthreads();
            hB = gate(hB);
            {
                const float oB = __shfl_xor(hB, 1);
                if (!(tid & 1)) {
                    const unsigned pB = (unsigned)f2bf(hB) | ((unsigned)f2bf(oB) << 16);
                    __hip_atomic_store((unsigned*)&hnext[(size_t)(b0B + r) * HID + j0 + c],
                                       pB, __ATOMIC_RELAXED, __HIP_MEMORY_SCOPE_SYSTEM);
                }
            }

            __syncthreads();
            ++phase;                       // after step s: phase = s + 2
            if (tid == 0)
                __hip_atomic_store(flagp, phase, __ATOMIC_RELAXED, __HIP_MEMORY_SCOPE_SYSTEM);
            if (wv == 0) {
                while (true) {
                    unsigned v = __hip_atomic_load(poll1, __ATOMIC_RELAXED,
                                                   __HIP_MEMORY_SCOPE_SYSTEM);
                    if (__all(v >= phase)) break;
                    __builtin_amdgcn_s_sleep(2);
                }
            } else if (wv == 1 && s + 1 < Tc) {
                const unsigned tgt = (unsigned)(s + 3);
                while (true) {
                    unsigned v = __hip_atomic_load(poll0, __ATOMIC_RELAXED,
                                                   __HIP_MEMORY_SCOPE_SYSTEM);
                    if (__all(v >= tgt)) break;
                    __builtin_amdgcn_s_sleep(2);
                }
            }
            __syncthreads();
        }

        h32_1[(size_t)(b0A + r) * HID + j0 + c] = hA;
        h32_1[(size_t)(b0B + r) * HID + j0 + c] = hB;
    }
}

// ---------------- tail (unchanged) ----------------
__global__ __launch_bounds__(256) void tail_kernel(
    const float* __restrict__ hfin,
    const float* __restrict__ bn_w, const float* __restrict__ bn_b,
    const float* __restrict__ bn_mean, const float* __restrict__ bn_var,
    const float* __restrict__ fc1_w, const float* __restrict__ fc1_b,
    const float* __restrict__ ln_w, const float* __restrict__ ln_b,
    const float* __restrict__ fc2_w, const float* __restrict__ fc2_b,
    float* __restrict__ out)
{
    const int b = blockIdx.x;
    const int tid = threadIdx.x;
    __shared__ float pn[512];
    __shared__ float o1[256];
    __shared__ float red[2][4];

    for (int jj = tid; jj < 512; jj += 256) {
        float v = hfin[(size_t)b * 512 + jj];
        v = (v - bn_mean[jj]) * rsqrtf(bn_var[jj] + EPSV) * bn_w[jj] + bn_b[jj];
        pn[jj] = v;
    }
    __syncthreads();

    const float4* w1 = (const float4*)(fc1_w + (size_t)tid * 512);
    float acc = fc1_b[tid];
#pragma unroll 4
    for (int kq = 0; kq < 128; ++kq) {
        float4 w4 = w1[kq];
        float4 h4 = *(const float4*)&pn[kq * 4];
        acc = fmaf(w4.x, h4.x, acc); acc = fmaf(w4.y, h4.y, acc);
        acc = fmaf(w4.z, h4.z, acc); acc = fmaf(w4.w, h4.w, acc);
    }
    const float val = fmaxf(acc, 0.f);

    float s = val, sq = val * val;
#pragma unroll
    for (int off = 32; off >= 1; off >>= 1) {
        s  += __shfl_xor(s, off);
        sq += __shfl_xor(sq, off);
    }
    const int wv = tid >> 6, ln = tid & 63;
    if (ln == 0) { red[0][wv] = s; red[1][wv] = sq; }
    __syncthreads();
    const float S  = red[0][0] + red[0][1] + red[0][2] + red[0][3];
    const float SQ = red[1][0] + red[1][1] + red[1][2] + red[1][3];
    const float mu  = S * (1.f / 256.f);
    const float var = SQ * (1.f / 256.f) - mu * mu;
    const float nv = (val - mu) * rsqrtf(var + EPSV) * ln_w[tid] + ln_b[tid];
    o1[tid] = nv;
    __syncthreads();

    if (wv < 3) {
        const float* w2 = fc2_w + wv * 256;
        float p = w2[ln] * o1[ln] + w2[ln + 64] * o1[ln + 64]
                + w2[ln + 128] * o1[ln + 128] + w2[ln + 192] * o1[ln + 192];
#pragma unroll
        for (int off = 32; off >= 1; off >>= 1) p += __shfl_xor(p, off);
        if (ln == 0) out[b * 3 + wv] = p + fc2_b[wv];
    }
}

extern "C" void kernel_launch(void* const* d_in, const int* in_sizes, int n_in,
                              void* d_out, int out_size, void* d_ws, size_t ws_size,
                              hipStream_t stream) {
    const float* x       = (const float*)d_in[0];
    const float* w_ih0   = (const float*)d_in[1];
    const float* w_hh0   = (const float*)d_in[2];
    const float* b_ih0   = (const float*)d_in[3];
    const float* b_hh0   = (const float*)d_in[4];
    const float* w_ih1   = (const float*)d_in[5];
    const float* w_hh1   = (const float*)d_in[6];
    const float* b_ih1   = (const float*)d_in[7];
    const float* b_hh1   = (const float*)d_in[8];
    const float* bn_w    = (const float*)d_in[9];
    const float* bn_b    = (const float*)d_in[10];
    const float* bn_mean = (const float*)d_in[11];
    const float* bn_var  = (const float*)d_in[12];
    const float* fc1_w   = (const float*)d_in[13];
    const float* fc1_b   = (const float*)d_in[14];
    const float* ln_w    = (const float*)d_in[15];
    const float* ln_b    = (const float*)d_in[16];
    const float* fc2_w   = (const float*)d_in[17];
    const float* fc2_b   = (const float*)d_in[18];
    float* out = (float*)d_out;

    // ws layout (float slots):
    // h32_0 | h32_1 | hbf0(2xB*H bf16) | hbf1 | y0bf(B*T*H bf16) | flags | xg chunk (bf16)
    float* ws = (float*)d_ws;
    const size_t h32F  = (size_t)BB * HID;            //     65,536
    const size_t hbfF  = (size_t)BB * HID;            // 2*B*H ushort = 65,536 slots
    const size_t y0bfF = (size_t)BB * TT * HID / 2;   // B*T*H ushort = 8,388,608 slots
    const size_t flgF  = 512;                         // flags0(256) + flags1(256)
    float*          h32_0 = ws;
    float*          h32_1 = h32_0 + h32F;
    unsigned short* hbf0  = (unsigned short*)(h32_1 + h32F);
    unsigned short* hbf1  = (unsigned short*)(h32_1 + h32F + hbfF);
    unsigned short* y0bf  = (unsigned short*)(h32_1 + h32F + 2 * hbfF);
    unsigned int*   flags = (unsigned int*)(h32_1 + h32F + 2 * hbfF + y0bfF);
    unsigned short* xgc   = (unsigned short*)(h32_1 + h32F + 2 * hbfF + y0bfF + flgF);
    unsigned int*   flags0 = flags;
    unsigned int*   flags1 = flags + 256;

    const size_t fixedF = 2 * h32F + 2 * hbfF + y0bfF + flgF;
    const size_t availF = ws_size / sizeof(float);
    int Tc = TT;
    while (Tc > 8 && fixedF + (size_t)BB * (size_t)Tc * G3 / 2 > availF) Tc >>= 1;

    for (int c = 0; c < TT; c += Tc) {
        gemm_mfma_bias<<<dim3(12, (BB * Tc) / 128), dim3(256), 0, stream>>>(
            x, w_ih0, b_ih0, xgc, IN0, c, Tc);
        hipMemsetAsync(flags, 0, flgF * sizeof(float), stream);
        int t0 = c, tc = Tc;
        void* args[] = { (void*)&xgc,
                         (void*)&w_hh0, (void*)&b_hh0,
                         (void*)&w_hh1, (void*)&b_hh1,
                         (void*)&w_ih1, (void*)&b_ih1,
                         (void*)&y0bf,
                         (void*)&h32_0, (void*)&h32_1,
                         (void*)&hbf0, (void*)&hbf1,
                         (void*)&flags0, (void*)&flags1,
                         (void*)&t0, (void*)&tc };
        hipLaunchCooperativeKernel((void*)fused_rec, dim3(256), dim3(256),
                                   args, 0, stream);
    }

    tail_kernel<<<dim3(128), dim3(256), 0, stream>>>(
        h32_1, bn_w, bn_b, bn_mean, bn_var,
        fc1_w, fc1_b, ln_w, ln_b, fc2_w, fc2_b, out);
}